// Round 5
// baseline (254.612 us; speedup 1.0000x reference)
//
#include <hip/hip_runtime.h>
#include <stdint.h>

// Problem constants: B=2, S=2048, HIDDEN=1024, NH=16, D=64
// M = B*S = 4096, N1 = 3072, K = 1024, N2 = 1024, BH = 32

#define DEV static __device__ __forceinline__

typedef unsigned short u16;
typedef __attribute__((ext_vector_type(4))) float f32x4;
typedef __attribute__((ext_vector_type(16))) float f32x16;
typedef __bf16 bf16x8 __attribute__((ext_vector_type(8)));
typedef __attribute__((ext_vector_type(8))) unsigned short u16x8;
typedef __attribute__((ext_vector_type(4))) unsigned short u16x4;

// 0.125 * log2(e): folded into Q so softmax weights are exp2(acc)
#define QSCALE 0.18033688011112042f

DEV u16 f2bf(float f) {
    unsigned u = __builtin_bit_cast(unsigned, f);
    u += 0x7fffu + ((u >> 16) & 1u);
    return (u16)(u >> 16);
}
DEV float bf2f(u16 h) {
    unsigned u = ((unsigned)h) << 16;
    return __builtin_bit_cast(float, u);
}

// async global->LDS, 16B per lane. LDS dest must be wave-uniform base + lane*16.
DEV void async_copy16(const void* g, void* l) {
    __builtin_amdgcn_global_load_lds(
        (__attribute__((address_space(1))) void*)(g),
        (__attribute__((address_space(3))) void*)(l), 16, 0, 0);
}

// ---------------- elementwise cast kernels ----------------

__global__ __launch_bounds__(256) void cast_f32_bf16(
    const float* __restrict__ src, u16* __restrict__ dst, int n4) {
    int i = blockIdx.x * 256 + threadIdx.x;
    if (i >= n4) return;
    f32x4 v = *(const f32x4*)(src + (size_t)i * 4);
    u16x4 o;
#pragma unroll
    for (int j = 0; j < 4; j++) o[j] = f2bf(v[j]);
    *(u16x4*)(dst + (size_t)i * 4) = o;
}

// src [rows][cols] fp32  ->  dst [cols][rows] bf16
__global__ __launch_bounds__(256) void transpose_cast(
    const float* __restrict__ src, u16* __restrict__ dst, int rows, int cols) {
    __shared__ float tile[32][33];
    int c0 = blockIdx.x * 32, r0 = blockIdx.y * 32;
    int tx = threadIdx.x, ty = threadIdx.y;  // block (32,8)
#pragma unroll
    for (int i = 0; i < 4; i++)
        tile[ty + i * 8][tx] = src[(size_t)(r0 + ty + i * 8) * cols + c0 + tx];
    __syncthreads();
#pragma unroll
    for (int i = 0; i < 4; i++)
        dst[(size_t)(c0 + ty + i * 8) * rows + r0 + tx] = f2bf(tile[tx][ty + i * 8]);
}

// ---------------- GEMM1: qkv projection ----------------
// 128x128 tile; LDS-transpose epilogue -> coalesced 16B stores into
// q/k/v [bh][s][d] bf16. n-range of each block lies in exactly one of
// q/k/v (n0 multiple of 128, sections are 1024-wide), so dst/scale are
// block-uniform.
__global__ __launch_bounds__(256) void gemm_qkv(
    const u16* __restrict__ A, const u16* __restrict__ Bt,
    u16* __restrict__ qb, u16* __restrict__ kb, u16* __restrict__ vb) {
    __shared__ __align__(16) u16 smem[128 * 136];  // 34 KB; aliases As/Bs/Cs
    u16* As = smem;            // [128][32]
    u16* Bs = smem + 4096;     // [128][32]
    const int t = threadIdx.x;
    const int wave = t >> 6;
    const int lane = t & 63;
    const int quad = lane >> 4;
    const int l16 = lane & 15;
    const int wr = wave >> 1;
    const int wc = wave & 1;
    const int m0 = blockIdx.y * 128;
    const int n0 = blockIdx.x * 128;

    f32x4 acc[4][4];
#pragma unroll
    for (int i = 0; i < 4; i++)
#pragma unroll
        for (int j = 0; j < 4; j++) acc[i][j] = {0.f, 0.f, 0.f, 0.f};

    for (int kt = 0; kt < 1024; kt += 32) {
#pragma unroll
        for (int i = 0; i < 2; i++) {
            int idx = i * 256 + t;
            int row = idx >> 2, kc = idx & 3;
            async_copy16(A + (size_t)(m0 + row) * 1024 + kt + kc * 8, &As[idx * 8]);
            async_copy16(Bt + (size_t)(n0 + row) * 1024 + kt + kc * 8, &Bs[idx * 8]);
        }
        __syncthreads();
        bf16x8 af[4], bfr[4];
#pragma unroll
        for (int mt = 0; mt < 4; mt++)
            af[mt] = *(const bf16x8*)&As[(wr * 64 + mt * 16 + l16) * 32 + quad * 8];
#pragma unroll
        for (int nt = 0; nt < 4; nt++)
            bfr[nt] = *(const bf16x8*)&Bs[(wc * 64 + nt * 16 + l16) * 32 + quad * 8];
#pragma unroll
        for (int mt = 0; mt < 4; mt++)
#pragma unroll
            for (int nt = 0; nt < 4; nt++)
                acc[mt][nt] = __builtin_amdgcn_mfma_f32_16x16x32_bf16(
                    af[mt], bfr[nt], acc[mt][nt], 0, 0, 0);
        __syncthreads();
    }

    // ---- epilogue: acc -> LDS [m][n] bf16 (stride 136) -> coalesced global
    const int tsel = n0 >> 10;  // 0=q 1=k 2=v (block-uniform)
    u16* dst = tsel == 0 ? qb : (tsel == 1 ? kb : vb);
    const float scl = tsel == 0 ? QSCALE : 1.0f;
#pragma unroll
    for (int mt = 0; mt < 4; mt++)
#pragma unroll
        for (int nt = 0; nt < 4; nt++) {
            int nn = wc * 64 + nt * 16 + l16;
#pragma unroll
            for (int r = 0; r < 4; r++) {
                int mm = wr * 64 + mt * 16 + quad * 4 + r;
                smem[mm * 136 + nn] = f2bf(acc[mt][nt][r] * scl);
            }
        }
    __syncthreads();
    const int col0 = (l16) * 8;       // 0..120, within one 64-d head (8-aligned)
    const int rowb = (t >> 4);        // 0..15
    const int h0 = (n0 & 1023) >> 6;  // first of the block's 2 heads
#pragma unroll
    for (int i = 0; i < 8; i++) {
        int row = i * 16 + rowb;      // 0..127
        u16x8 v = *(const u16x8*)&smem[row * 136 + col0];
        int h = h0 + (col0 >> 6), d = col0 & 63;
        int mm = m0 + row;
        int b = mm >> 11, s = mm & 2047;
        *(u16x8*)&dst[((size_t)((b * 16 + h) * 2048 + s)) * 64 + d] = v;
    }
}

// GEMM2: out = values @ w_o, fp32 output. 64x128 tiles -> 512 blocks (2/CU)
// so a co-resident block covers each barrier drain.
__global__ __launch_bounds__(256) void gemm_out(
    const u16* __restrict__ A, const u16* __restrict__ Bt,
    float* __restrict__ out) {
    __shared__ __align__(16) u16 As[64 * 32];
    __shared__ __align__(16) u16 Bs[128 * 32];
    const int m0 = blockIdx.y * 64;
    const int n0 = blockIdx.x * 128;
    const int t = threadIdx.x;
    const int wave = t >> 6, lane = t & 63;
    const int quad = lane >> 4, l16 = lane & 15;
    const int wr = wave >> 1, wc = wave & 1;  // wave tile: 32 rows x 64 cols

    f32x4 acc[2][4];
#pragma unroll
    for (int i = 0; i < 2; i++)
#pragma unroll
        for (int j = 0; j < 4; j++) acc[i][j] = {0.f, 0.f, 0.f, 0.f};

    for (int kt = 0; kt < 1024; kt += 32) {
        async_copy16(A + (size_t)(m0 + (t >> 2)) * 1024 + kt + (t & 3) * 8, &As[t * 8]);
#pragma unroll
        for (int i = 0; i < 2; i++) {
            int idx = i * 256 + t;
            int row = idx >> 2, kc = idx & 3;
            async_copy16(Bt + (size_t)(n0 + row) * 1024 + kt + kc * 8, &Bs[idx * 8]);
        }
        __syncthreads();
        bf16x8 af[2], bfr[4];
#pragma unroll
        for (int mt = 0; mt < 2; mt++)
            af[mt] = *(const bf16x8*)&As[(wr * 32 + mt * 16 + l16) * 32 + quad * 8];
#pragma unroll
        for (int nt = 0; nt < 4; nt++)
            bfr[nt] = *(const bf16x8*)&Bs[(wc * 64 + nt * 16 + l16) * 32 + quad * 8];
#pragma unroll
        for (int mt = 0; mt < 2; mt++)
#pragma unroll
            for (int nt = 0; nt < 4; nt++)
                acc[mt][nt] = __builtin_amdgcn_mfma_f32_16x16x32_bf16(
                    af[mt], bfr[nt], acc[mt][nt], 0, 0, 0);
        __syncthreads();
    }
#pragma unroll
    for (int nt = 0; nt < 4; nt++) {
        int nn = n0 + wc * 64 + nt * 16 + l16;
#pragma unroll
        for (int mt = 0; mt < 2; mt++) {
#pragma unroll
            for (int r = 0; r < 4; r++) {
                int mm = m0 + wr * 32 + mt * 16 + quad * 4 + r;
                out[(size_t)mm * 1024 + nn] = acc[mt][nt][r];
            }
        }
    }
}

// ---------------- attention passes -----------------------------------------
// No max subtraction: scores are O(+-5); exp(s)/sum(exp(s)) == softmax.
// Q pre-scaled by 0.125*log2e so weights are exp2(acc).
// 32x32x16 layouts: A/B [row=lane&31][k=f*16+(lane>>5)*8+j];
// C/D col=lane&31, row=(r&3)+8*(r>>2)+4*(lane>>5).
//
// R3 lesson: conflict-fix, occupancy, LDS-volume all throughput-neutral ->
// stall-bound. R4: the per-tile __syncthreads() emitted s_waitcnt vmcnt(0),
// draining the prefetch it was supposed to overlap (m97 barrier-drain
// pathology). Replace with T4 counted-vmcnt (m201 derived-wait): after
// issuing STAGE(t+1) (4 gload_lds/thread, LAST vmem issued), s_waitcnt
// vmcnt(4) retires oldest-first -> tile t landed, t+1 stays in flight
// ACROSS the raw s_barrier. barrier-2 after compute guards dbuf overwrite.

#define WAIT_VMCNT_4 { asm volatile("s_waitcnt vmcnt(4)" ::: "memory"); \
                       __builtin_amdgcn_sched_barrier(0); }
#define WAIT_VMCNT_0 { asm volatile("s_waitcnt vmcnt(0)" ::: "memory"); \
                       __builtin_amdgcn_sched_barrier(0); }

// Pass 1: block = 4 waves x 64 q-rows = 256 q-rows; k-chunk = 512 rows,
// staged as 4 tiles of 128 (XOR-swizzled, double-buffered). lp: 4 partials.
__global__ __launch_bounds__(256) void attn_pass1(
    const u16* __restrict__ qb, const u16* __restrict__ kb,
    float* __restrict__ lp) {
    __shared__ __align__(16) u16 Ks[2][128 * 64];  // 2 x 16 KB, XOR-swizzled
    const int t = threadIdx.x;
    const int wave = t >> 6;
    const int lane = t & 63;
    const int l32 = lane & 31, half = lane >> 5;
    const int kchunk = blockIdx.x & 3;        // 512 k-rows each
    const int qblk = (blockIdx.x >> 2) & 7;   // 256 q-rows each
    const int bh = blockIdx.x >> 5;
    const int q0 = qblk * 256 + wave * 64;

    // persistent Q fragments, 2 q-sets: A[m=l32][k=f*16+half*8+j]
    bf16x8 a[2][4];
#pragma unroll
    for (int qs = 0; qs < 2; qs++) {
        const u16* Qr = qb + (size_t)(bh * 2048 + q0 + qs * 32 + l32) * 64 + half * 8;
#pragma unroll
        for (int f = 0; f < 4; f++) a[qs][f] = *(const bf16x8*)&Qr[f * 16];
    }

    const u16* Kbase = kb + (size_t)(bh * 2048 + kchunk * 512) * 64;

    float lsum[2][16];
#pragma unroll
    for (int qs = 0; qs < 2; qs++)
#pragma unroll
        for (int r = 0; r < 16; r++) lsum[qs][r] = 0.f;

    f32x16 ZZ;
#pragma unroll
    for (int r = 0; r < 16; r++) ZZ[r] = 0.f;

    // STAGE one 128-row tile: LDS[row][blk] = G[row][blk ^ (row&7)]
#define STAGE_K(buf, kt)                                                        \
    {                                                                           \
        _Pragma("unroll") for (int i = 0; i < 4; i++) {                         \
            int idx = i * 256 + t;                                              \
            int row = idx >> 3;                                                 \
            int blk = (idx & 7) ^ (row & 7);                                    \
            async_copy16(Kbase + (size_t)((kt) * 128 + row) * 64 + blk * 8,     \
                         &Ks[buf][idx * 8]);                                    \
        }                                                                       \
    }

    STAGE_K(0, 0);

#pragma unroll
    for (int kt = 0; kt < 4; kt++) {
        const int cur = kt & 1;
        if (kt < 3) {
            STAGE_K(cur ^ 1, kt + 1);   // last vmem issued before the wait
            WAIT_VMCNT_4;               // tile kt landed; kt+1 stays in flight
        } else {
            WAIT_VMCNT_0;
        }
        __builtin_amdgcn_s_barrier();   // publish tile kt block-wide
#pragma unroll
        for (int sub = 0; sub < 4; sub++) {
            const int row = sub * 32 + l32;
            const int r7 = row & 7;
            bf16x8 bfr[4];
#pragma unroll
            for (int f = 0; f < 4; f++)
                bfr[f] = *(const bf16x8*)&Ks[cur][row * 64 + ((f * 2 + half) ^ r7) * 8];
            __builtin_amdgcn_s_setprio(1);
#pragma unroll
            for (int qs = 0; qs < 2; qs++) {
                f32x16 acc = __builtin_amdgcn_mfma_f32_32x32x16_bf16(
                    a[qs][0], bfr[0], ZZ, 0, 0, 0);
#pragma unroll
                for (int f = 1; f < 4; f++)
                    acc = __builtin_amdgcn_mfma_f32_32x32x16_bf16(
                        a[qs][f], bfr[f], acc, 0, 0, 0);
                __builtin_amdgcn_s_setprio(0);
#pragma unroll
                for (int r = 0; r < 16; r++)
                    lsum[qs][r] += __builtin_amdgcn_exp2f(acc[r]);
                __builtin_amdgcn_s_setprio(1);
            }
            __builtin_amdgcn_s_setprio(0);
        }
        __builtin_amdgcn_s_barrier();   // all reads of Ks[cur] done -> reusable
    }
    // reduce each row across the 32 k-columns (lanes within each half)
#pragma unroll
    for (int qs = 0; qs < 2; qs++) {
#pragma unroll
        for (int r = 0; r < 16; r++) {
            float v = lsum[qs][r];
            v += __shfl_xor(v, 1);
            v += __shfl_xor(v, 2);
            v += __shfl_xor(v, 4);
            v += __shfl_xor(v, 8);
            v += __shfl_xor(v, 16);
            lsum[qs][r] = v;
        }
    }
    if (l32 == 0) {
#pragma unroll
        for (int qs = 0; qs < 2; qs++) {
            float* dst = lp + kchunk * 65536 + bh * 2048 + q0 + qs * 32 + half * 4;
#pragma unroll
            for (int r = 0; r < 16; r++)
                dst[(r & 3) + 8 * (r >> 2)] = lsum[qs][r];
        }
    }
}

// Pass 2: block = 4 waves x 64 k-cols = 256 k-cols; q-chunk = 512 rows,
// staged as 4 tiles of 128; li = 1/(sum of 4 lp partials) in LDS.
__global__ __launch_bounds__(256) void attn_pass2(
    const u16* __restrict__ qb, const u16* __restrict__ kb,
    const float* __restrict__ lp, float* __restrict__ cp) {
    __shared__ __align__(16) u16 Qs[2][128 * 64];  // 2 x 16 KB, XOR-swizzled
    __shared__ __align__(16) float li_lds[512];
    const int t = threadIdx.x;
    const int wave = t >> 6;
    const int lane = t & 63;
    const int l32 = lane & 31, half = lane >> 5;
    const int qchunk = blockIdx.x & 3;        // 512 q-rows each
    const int kblk = (blockIdx.x >> 2) & 7;   // 256 k-cols each
    const int bh = blockIdx.x >> 5;
    const int k0 = kblk * 256 + wave * 64;

    // li table for this block's 512 q-rows
    {
        const int base = bh * 2048 + qchunk * 512;
#pragma unroll
        for (int i = 0; i < 2; i++) {
            int q = i * 256 + t;
            float s = lp[base + q] + lp[65536 + base + q] + lp[131072 + base + q] +
                      lp[196608 + base + q];
            li_lds[q] = 1.0f / s;
        }
    }

    // persistent K fragments, 2 k-sets: B[n=l32][k=f*16+half*8+j]
    bf16x8 b[2][4];
#pragma unroll
    for (int ks = 0; ks < 2; ks++) {
        const u16* Kr = kb + (size_t)(bh * 2048 + k0 + ks * 32 + l32) * 64 + half * 8;
#pragma unroll
        for (int f = 0; f < 4; f++) b[ks][f] = *(const bf16x8*)&Kr[f * 16];
    }

    const u16* Qbase = qb + (size_t)(bh * 2048 + qchunk * 512) * 64;

    f32x16 ZZ;
#pragma unroll
    for (int r = 0; r < 16; r++) ZZ[r] = 0.f;

#define STAGE_Q(buf, qt)                                                        \
    {                                                                           \
        _Pragma("unroll") for (int i = 0; i < 4; i++) {                         \
            int idx = i * 256 + t;                                              \
            int row = idx >> 3;                                                 \
            int blk = (idx & 7) ^ (row & 7);                                    \
            async_copy16(Qbase + (size_t)((qt) * 128 + row) * 64 + blk * 8,     \
                         &Qs[buf][idx * 8]);                                    \
        }                                                                       \
    }

    float cs[2] = {0.f, 0.f};
    __syncthreads();      // li_lds visible (drains only lp loads; STAGE not yet issued)
    STAGE_Q(0, 0);

#pragma unroll
    for (int qt = 0; qt < 4; qt++) {
        const int cur = qt & 1;
        if (qt < 3) {
            STAGE_Q(cur ^ 1, qt + 1);   // last vmem issued before the wait
            WAIT_VMCNT_4;               // tile qt landed; qt+1 stays in flight
        } else {
            WAIT_VMCNT_0;
        }
        __builtin_amdgcn_s_barrier();   // publish tile qt block-wide
#pragma unroll
        for (int sub = 0; sub < 4; sub++) {
            const int row = sub * 32 + l32;
            const int r7 = row & 7;
            bf16x8 af[4];
#pragma unroll
            for (int f = 0; f < 4; f++)
                af[f] = *(const bf16x8*)&Qs[cur][row * 64 + ((f * 2 + half) ^ r7) * 8];
            const float* lr = &li_lds[qt * 128 + sub * 32 + half * 4];
            f32x4 li0 = *(const f32x4*)&lr[0];
            f32x4 li1 = *(const f32x4*)&lr[8];
            f32x4 li2 = *(const f32x4*)&lr[16];
            f32x4 li3 = *(const f32x4*)&lr[24];
            __builtin_amdgcn_s_setprio(1);
#pragma unroll
            for (int ks = 0; ks < 2; ks++) {
                f32x16 acc = __builtin_amdgcn_mfma_f32_32x32x16_bf16(
                    af[0], b[ks][0], ZZ, 0, 0, 0);
#pragma unroll
                for (int f = 1; f < 4; f++)
                    acc = __builtin_amdgcn_mfma_f32_32x32x16_bf16(
                        af[f], b[ks][f], acc, 0, 0, 0);
                __builtin_amdgcn_s_setprio(0);
                float c = cs[ks];
#pragma unroll
                for (int r = 0; r < 4; r++) c += __builtin_amdgcn_exp2f(acc[r]) * li0[r];
#pragma unroll
                for (int r = 0; r < 4; r++) c += __builtin_amdgcn_exp2f(acc[4 + r]) * li1[r];
#pragma unroll
                for (int r = 0; r < 4; r++) c += __builtin_amdgcn_exp2f(acc[8 + r]) * li2[r];
#pragma unroll
                for (int r = 0; r < 4; r++) c += __builtin_amdgcn_exp2f(acc[12 + r]) * li3[r];
                cs[ks] = c;
                __builtin_amdgcn_s_setprio(1);
            }
            __builtin_amdgcn_s_setprio(0);
        }
        __builtin_amdgcn_s_barrier();   // all reads of Qs[cur] done -> reusable
    }
#pragma unroll
    for (int ks = 0; ks < 2; ks++) {
        float v = cs[ks] + __shfl_xor(cs[ks], 32);
        if (lane < 32)
            cp[qchunk * 65536 + bh * 2048 + k0 + ks * 32 + lane] = v;
    }
}

// values[b][s][h*64+d] = colsum[bh][s] * v[bh][s][d]  (bf16); sums 4 partials
__global__ __launch_bounds__(256) void scale_v(
    const u16* __restrict__ vb, const float* __restrict__ cp,
    u16* __restrict__ valsb) {
    int tid = blockIdx.x * 256 + threadIdx.x;  // 524288 threads, 8 elems each
    int base = tid << 3;
    int bh = base >> 17;           // / (2048*64)
    int rem = base & 131071;
    int s = rem >> 6;
    int d0 = rem & 63;
    int ci = bh * 2048 + s;
    float cs = cp[ci] + cp[65536 + ci] + cp[131072 + ci] + cp[196608 + ci];
    u16x8 v = *(const u16x8*)(vb + (size_t)base);
    u16x8 o;
#pragma unroll
    for (int i = 0; i < 8; i++) o[i] = f2bf(bf2f(v[i]) * cs);
    int b = bh >> 4, h = bh & 15;
    *(u16x8*)&valsb[(size_t)((b * 2048 + s) * 1024) + h * 64 + d0] = o;
}

// ---------------- launch ----------------

extern "C" void kernel_launch(void* const* d_in, const int* in_sizes, int n_in,
                              void* d_out, int out_size, void* d_ws, size_t ws_size,
                              hipStream_t stream) {
    const float* x    = (const float*)d_in[0];   // [2,2048,1024]
    const float* wqkv = (const float*)d_in[1];   // [1024,3072]
    const float* wo   = (const float*)d_in[2];   // [1024,1024]
    float* out = (float*)d_out;                  // [2,2048,1024] fp32
    char* ws = (char*)d_ws;

    u16* xb      = (u16*)(ws);                   // [4096][1024] bf16 (dead after gemm_qkv)
    u16* wqkvT   = (u16*)(ws + 8388608);         // [3072][1024] bf16
    u16* woT     = (u16*)(ws + 14680064);        // [1024][1024] bf16
    u16* qb      = (u16*)(ws + 16777216);        // [32][2048][64] bf16
    u16* kb      = (u16*)(ws + 25165824);
    u16* vb      = (u16*)(ws + 33554432);
    u16* valsb   = (u16*)(ws + 42467328);        // [4096][1024] bf16
    // partial buffers alias xb (dead after gemm_qkv)
    float* lp    = (float*)(ws);                 // [4][32][2048]
    float* cp    = (float*)(ws + 1048576);       // [4][32][2048]

    cast_f32_bf16<<<4096, 256, 0, stream>>>(x, xb, 1048576);
    transpose_cast<<<dim3(96, 32), dim3(32, 8), 0, stream>>>(wqkv, wqkvT, 1024, 3072);
    transpose_cast<<<dim3(32, 32), dim3(32, 8), 0, stream>>>(wo, woT, 1024, 1024);
    gemm_qkv<<<dim3(24, 32), 256, 0, stream>>>(xb, wqkvT, qb, kb, vb);
    attn_pass1<<<1024, 256, 0, stream>>>(qb, kb, lp);
    attn_pass2<<<1024, 256, 0, stream>>>(qb, kb, lp, cp);
    scale_v<<<2048, 256, 0, stream>>>(vb, cp, valsb);
    gemm_out<<<dim3(8, 64), 256, 0, stream>>>(valsb, woT, out);
}

// Round 6
// 199.095 us; speedup vs baseline: 1.2788x; 1.2788x over previous
//
#include <hip/hip_runtime.h>
#include <stdint.h>

// Problem constants: B=2, S=2048, HIDDEN=1024, NH=16, D=64
// M = B*S = 4096, N1 = 3072, K = 1024, N2 = 1024, BH = 32

#define DEV static __device__ __forceinline__

typedef unsigned short u16;
typedef __attribute__((ext_vector_type(4))) float f32x4;
typedef __attribute__((ext_vector_type(16))) float f32x16;
typedef __bf16 bf16x8 __attribute__((ext_vector_type(8)));
typedef __attribute__((ext_vector_type(8))) unsigned short u16x8;
typedef __attribute__((ext_vector_type(4))) unsigned short u16x4;

// 0.125 * log2(e): folded into Q so softmax weights are exp2(acc)
#define QSCALE 0.18033688011112042f

DEV u16 f2bf(float f) {
    unsigned u = __builtin_bit_cast(unsigned, f);
    u += 0x7fffu + ((u >> 16) & 1u);
    return (u16)(u >> 16);
}
DEV float bf2f(u16 h) {
    unsigned u = ((unsigned)h) << 16;
    return __builtin_bit_cast(float, u);
}

// async global->LDS, 16B per lane. LDS dest must be wave-uniform base + lane*16.
DEV void async_copy16(const void* g, void* l) {
    __builtin_amdgcn_global_load_lds(
        (__attribute__((address_space(1))) void*)(g),
        (__attribute__((address_space(3))) void*)(l), 16, 0, 0);
}

// ---------------- elementwise cast kernels ----------------

__global__ __launch_bounds__(256) void cast_f32_bf16(
    const float* __restrict__ src, u16* __restrict__ dst, int n4) {
    int i = blockIdx.x * 256 + threadIdx.x;
    if (i >= n4) return;
    f32x4 v = *(const f32x4*)(src + (size_t)i * 4);
    u16x4 o;
#pragma unroll
    for (int j = 0; j < 4; j++) o[j] = f2bf(v[j]);
    *(u16x4*)(dst + (size_t)i * 4) = o;
}

// src [rows][cols] fp32  ->  dst [cols][rows] bf16
__global__ __launch_bounds__(256) void transpose_cast(
    const float* __restrict__ src, u16* __restrict__ dst, int rows, int cols) {
    __shared__ float tile[32][33];
    int c0 = blockIdx.x * 32, r0 = blockIdx.y * 32;
    int tx = threadIdx.x, ty = threadIdx.y;  // block (32,8)
#pragma unroll
    for (int i = 0; i < 4; i++)
        tile[ty + i * 8][tx] = src[(size_t)(r0 + ty + i * 8) * cols + c0 + tx];
    __syncthreads();
#pragma unroll
    for (int i = 0; i < 4; i++)
        dst[(size_t)(c0 + ty + i * 8) * rows + r0 + tx] = f2bf(tile[tx][ty + i * 8]);
}

// ---------------- GEMM1: qkv projection ----------------
// 128x128 tile; LDS-transpose epilogue -> coalesced 16B stores into
// q/k/v [bh][s][d] bf16. n-range of each block lies in exactly one of
// q/k/v (n0 multiple of 128, sections are 1024-wide), so dst/scale are
// block-uniform.
__global__ __launch_bounds__(256) void gemm_qkv(
    const u16* __restrict__ A, const u16* __restrict__ Bt,
    u16* __restrict__ qb, u16* __restrict__ kb, u16* __restrict__ vb) {
    __shared__ __align__(16) u16 smem[128 * 136];  // 34 KB; aliases As/Bs/Cs
    u16* As = smem;            // [128][32]
    u16* Bs = smem + 4096;     // [128][32]
    const int t = threadIdx.x;
    const int wave = t >> 6;
    const int lane = t & 63;
    const int quad = lane >> 4;
    const int l16 = lane & 15;
    const int wr = wave >> 1;
    const int wc = wave & 1;
    const int m0 = blockIdx.y * 128;
    const int n0 = blockIdx.x * 128;

    f32x4 acc[4][4];
#pragma unroll
    for (int i = 0; i < 4; i++)
#pragma unroll
        for (int j = 0; j < 4; j++) acc[i][j] = {0.f, 0.f, 0.f, 0.f};

    for (int kt = 0; kt < 1024; kt += 32) {
#pragma unroll
        for (int i = 0; i < 2; i++) {
            int idx = i * 256 + t;
            int row = idx >> 2, kc = idx & 3;
            async_copy16(A + (size_t)(m0 + row) * 1024 + kt + kc * 8, &As[idx * 8]);
            async_copy16(Bt + (size_t)(n0 + row) * 1024 + kt + kc * 8, &Bs[idx * 8]);
        }
        __syncthreads();
        bf16x8 af[4], bfr[4];
#pragma unroll
        for (int mt = 0; mt < 4; mt++)
            af[mt] = *(const bf16x8*)&As[(wr * 64 + mt * 16 + l16) * 32 + quad * 8];
#pragma unroll
        for (int nt = 0; nt < 4; nt++)
            bfr[nt] = *(const bf16x8*)&Bs[(wc * 64 + nt * 16 + l16) * 32 + quad * 8];
#pragma unroll
        for (int mt = 0; mt < 4; mt++)
#pragma unroll
            for (int nt = 0; nt < 4; nt++)
                acc[mt][nt] = __builtin_amdgcn_mfma_f32_16x16x32_bf16(
                    af[mt], bfr[nt], acc[mt][nt], 0, 0, 0);
        __syncthreads();
    }

    // ---- epilogue: acc -> LDS [m][n] bf16 (stride 136) -> coalesced global
    const int tsel = n0 >> 10;  // 0=q 1=k 2=v (block-uniform)
    u16* dst = tsel == 0 ? qb : (tsel == 1 ? kb : vb);
    const float scl = tsel == 0 ? QSCALE : 1.0f;
#pragma unroll
    for (int mt = 0; mt < 4; mt++)
#pragma unroll
        for (int nt = 0; nt < 4; nt++) {
            int nn = wc * 64 + nt * 16 + l16;
#pragma unroll
            for (int r = 0; r < 4; r++) {
                int mm = wr * 64 + mt * 16 + quad * 4 + r;
                smem[mm * 136 + nn] = f2bf(acc[mt][nt][r] * scl);
            }
        }
    __syncthreads();
    const int col0 = (l16) * 8;       // 0..120, within one 64-d head (8-aligned)
    const int rowb = (t >> 4);        // 0..15
    const int h0 = (n0 & 1023) >> 6;  // first of the block's 2 heads
#pragma unroll
    for (int i = 0; i < 8; i++) {
        int row = i * 16 + rowb;      // 0..127
        u16x8 v = *(const u16x8*)&smem[row * 136 + col0];
        int h = h0 + (col0 >> 6), d = col0 & 63;
        int mm = m0 + row;
        int b = mm >> 11, s = mm & 2047;
        *(u16x8*)&dst[((size_t)((b * 16 + h) * 2048 + s)) * 64 + d] = v;
    }
}

// GEMM2: out = values @ w_o, fp32 output. 64x128 tiles -> 512 blocks (2/CU)
// so a co-resident block covers each barrier drain.
__global__ __launch_bounds__(256) void gemm_out(
    const u16* __restrict__ A, const u16* __restrict__ Bt,
    float* __restrict__ out) {
    __shared__ __align__(16) u16 As[64 * 32];
    __shared__ __align__(16) u16 Bs[128 * 32];
    const int m0 = blockIdx.y * 64;
    const int n0 = blockIdx.x * 128;
    const int t = threadIdx.x;
    const int wave = t >> 6, lane = t & 63;
    const int quad = lane >> 4, l16 = lane & 15;
    const int wr = wave >> 1, wc = wave & 1;  // wave tile: 32 rows x 64 cols

    f32x4 acc[2][4];
#pragma unroll
    for (int i = 0; i < 2; i++)
#pragma unroll
        for (int j = 0; j < 4; j++) acc[i][j] = {0.f, 0.f, 0.f, 0.f};

    for (int kt = 0; kt < 1024; kt += 32) {
        async_copy16(A + (size_t)(m0 + (t >> 2)) * 1024 + kt + (t & 3) * 8, &As[t * 8]);
#pragma unroll
        for (int i = 0; i < 2; i++) {
            int idx = i * 256 + t;
            int row = idx >> 2, kc = idx & 3;
            async_copy16(Bt + (size_t)(n0 + row) * 1024 + kt + kc * 8, &Bs[idx * 8]);
        }
        __syncthreads();
        bf16x8 af[2], bfr[4];
#pragma unroll
        for (int mt = 0; mt < 2; mt++)
            af[mt] = *(const bf16x8*)&As[(wr * 32 + mt * 16 + l16) * 32 + quad * 8];
#pragma unroll
        for (int nt = 0; nt < 4; nt++)
            bfr[nt] = *(const bf16x8*)&Bs[(wc * 64 + nt * 16 + l16) * 32 + quad * 8];
#pragma unroll
        for (int mt = 0; mt < 2; mt++)
#pragma unroll
            for (int nt = 0; nt < 4; nt++)
                acc[mt][nt] = __builtin_amdgcn_mfma_f32_16x16x32_bf16(
                    af[mt], bfr[nt], acc[mt][nt], 0, 0, 0);
        __syncthreads();
    }
#pragma unroll
    for (int nt = 0; nt < 4; nt++) {
        int nn = n0 + wc * 64 + nt * 16 + l16;
#pragma unroll
        for (int mt = 0; mt < 2; mt++) {
#pragma unroll
            for (int r = 0; r < 4; r++) {
                int mm = m0 + wr * 32 + mt * 16 + quad * 4 + r;
                out[(size_t)mm * 1024 + nn] = acc[mt][nt][r];
            }
        }
    }
}

// ---------------- attention passes -----------------------------------------
// No max subtraction: scores are O(+-5); exp(s)/sum(exp(s)) == softmax.
// Q pre-scaled by 0.125*log2e so weights are exp2(acc).
// 32x32x16 layouts: A/B [row=lane&31][k=f*16+(lane>>5)*8+j];
// C/D col=lane&31, row=(r&3)+8*(r>>2)+4*(lane>>5).
//
// R5 lesson: #pragma unroll(outer) + sched_barrier(0) blew VGPR to 256 and
// spilled (WRITE_SIZE 89MB = scratch). R6: same counted-vmcnt pipeline but
// codegen-safe: rolled loop + peeled last iter; ONE fused asm
// "s_waitcnt vmcnt(4); s_barrier" with "memory" clobber (same clobber
// semantics as __syncthreads, so codegen matches R3 except the wait count).
// vmcnt retires oldest-first: STAGE(t+1) is the last vmem issued before the
// wait, so vmcnt(4) => tile t landed, t+1 in flight ACROSS the barrier.
// Trailing bare s_barrier guards the double-buffer overwrite.

#define WAITBAR_4 asm volatile("s_waitcnt vmcnt(4)\n\ts_barrier" ::: "memory")
#define WAITBAR_0 asm volatile("s_waitcnt vmcnt(0)\n\ts_barrier" ::: "memory")
#define BAR_ONLY  asm volatile("s_barrier" ::: "memory")

// Pass 1: block = 4 waves x 64 q-rows = 256 q-rows; k-chunk = 512 rows,
// staged as 4 tiles of 128 (XOR-swizzled, double-buffered). lp: 4 partials.
__global__ __launch_bounds__(256) void attn_pass1(
    const u16* __restrict__ qb, const u16* __restrict__ kb,
    float* __restrict__ lp) {
    __shared__ __align__(16) u16 Ks[2][128 * 64];  // 2 x 16 KB, XOR-swizzled
    const int t = threadIdx.x;
    const int wave = t >> 6;
    const int lane = t & 63;
    const int l32 = lane & 31, half = lane >> 5;
    const int kchunk = blockIdx.x & 3;        // 512 k-rows each
    const int qblk = (blockIdx.x >> 2) & 7;   // 256 q-rows each
    const int bh = blockIdx.x >> 5;
    const int q0 = qblk * 256 + wave * 64;

    // persistent Q fragments, 2 q-sets: A[m=l32][k=f*16+half*8+j]
    bf16x8 a[2][4];
#pragma unroll
    for (int qs = 0; qs < 2; qs++) {
        const u16* Qr = qb + (size_t)(bh * 2048 + q0 + qs * 32 + l32) * 64 + half * 8;
#pragma unroll
        for (int f = 0; f < 4; f++) a[qs][f] = *(const bf16x8*)&Qr[f * 16];
    }

    const u16* Kbase = kb + (size_t)(bh * 2048 + kchunk * 512) * 64;

    float lsum[2][16];
#pragma unroll
    for (int qs = 0; qs < 2; qs++)
#pragma unroll
        for (int r = 0; r < 16; r++) lsum[qs][r] = 0.f;

    f32x16 ZZ;
#pragma unroll
    for (int r = 0; r < 16; r++) ZZ[r] = 0.f;

    // STAGE one 128-row tile: LDS[row][blk] = G[row][blk ^ (row&7)]
#define STAGE_K(buf, kt)                                                        \
    {                                                                           \
        _Pragma("unroll") for (int i = 0; i < 4; i++) {                         \
            int idx = i * 256 + t;                                              \
            int row = idx >> 3;                                                 \
            int blk = (idx & 7) ^ (row & 7);                                    \
            async_copy16(Kbase + (size_t)((kt) * 128 + row) * 64 + blk * 8,     \
                         &Ks[buf][idx * 8]);                                    \
        }                                                                       \
    }

#define COMPUTE_K(cur)                                                          \
    {                                                                           \
        _Pragma("unroll") for (int sub = 0; sub < 4; sub++) {                   \
            const int row = sub * 32 + l32;                                     \
            const int r7 = row & 7;                                             \
            bf16x8 bfr[4];                                                      \
            _Pragma("unroll") for (int f = 0; f < 4; f++)                       \
                bfr[f] = *(const bf16x8*)&Ks[cur][row * 64 +                    \
                                                 (((f * 2 + half)) ^ r7) * 8];  \
            __builtin_amdgcn_s_setprio(1);                                      \
            _Pragma("unroll") for (int qs = 0; qs < 2; qs++) {                  \
                f32x16 acc = __builtin_amdgcn_mfma_f32_32x32x16_bf16(           \
                    a[qs][0], bfr[0], ZZ, 0, 0, 0);                             \
                _Pragma("unroll") for (int f = 1; f < 4; f++)                   \
                    acc = __builtin_amdgcn_mfma_f32_32x32x16_bf16(              \
                        a[qs][f], bfr[f], acc, 0, 0, 0);                        \
                __builtin_amdgcn_s_setprio(0);                                  \
                _Pragma("unroll") for (int r = 0; r < 16; r++)                  \
                    lsum[qs][r] += __builtin_amdgcn_exp2f(acc[r]);              \
                __builtin_amdgcn_s_setprio(1);                                  \
            }                                                                   \
            __builtin_amdgcn_s_setprio(0);                                     \
        }                                                                       \
    }

    STAGE_K(0, 0);
    for (int kt = 0; kt < 3; kt++) {   // rolled: small code, low VGPR
        const int cur = kt & 1;
        STAGE_K(cur ^ 1, kt + 1);      // last vmem issued before the wait
        WAITBAR_4;                     // tile kt landed; kt+1 in flight
        COMPUTE_K(cur);
        BAR_ONLY;                      // Ks[cur] reads done -> reusable
    }
    WAITBAR_0;                         // peeled last tile (3) in buf 1
    COMPUTE_K(1);

    // reduce each row across the 32 k-columns (lanes within each half)
#pragma unroll
    for (int qs = 0; qs < 2; qs++) {
#pragma unroll
        for (int r = 0; r < 16; r++) {
            float v = lsum[qs][r];
            v += __shfl_xor(v, 1);
            v += __shfl_xor(v, 2);
            v += __shfl_xor(v, 4);
            v += __shfl_xor(v, 8);
            v += __shfl_xor(v, 16);
            lsum[qs][r] = v;
        }
    }
    if (l32 == 0) {
#pragma unroll
        for (int qs = 0; qs < 2; qs++) {
            float* dst = lp + kchunk * 65536 + bh * 2048 + q0 + qs * 32 + half * 4;
#pragma unroll
            for (int r = 0; r < 16; r++)
                dst[(r & 3) + 8 * (r >> 2)] = lsum[qs][r];
        }
    }
}

// Pass 2: block = 4 waves x 64 k-cols = 256 k-cols; q-chunk = 512 rows,
// staged as 4 tiles of 128; li = 1/(sum of 4 lp partials) in LDS.
__global__ __launch_bounds__(256) void attn_pass2(
    const u16* __restrict__ qb, const u16* __restrict__ kb,
    const float* __restrict__ lp, float* __restrict__ cp) {
    __shared__ __align__(16) u16 Qs[2][128 * 64];  // 2 x 16 KB, XOR-swizzled
    __shared__ __align__(16) float li_lds[512];
    const int t = threadIdx.x;
    const int wave = t >> 6;
    const int lane = t & 63;
    const int l32 = lane & 31, half = lane >> 5;
    const int qchunk = blockIdx.x & 3;        // 512 q-rows each
    const int kblk = (blockIdx.x >> 2) & 7;   // 256 k-cols each
    const int bh = blockIdx.x >> 5;
    const int k0 = kblk * 256 + wave * 64;

    // li table for this block's 512 q-rows
    {
        const int base = bh * 2048 + qchunk * 512;
#pragma unroll
        for (int i = 0; i < 2; i++) {
            int q = i * 256 + t;
            float s = lp[base + q] + lp[65536 + base + q] + lp[131072 + base + q] +
                      lp[196608 + base + q];
            li_lds[q] = 1.0f / s;
        }
    }

    // persistent K fragments, 2 k-sets: B[n=l32][k=f*16+half*8+j]
    bf16x8 b[2][4];
#pragma unroll
    for (int ks = 0; ks < 2; ks++) {
        const u16* Kr = kb + (size_t)(bh * 2048 + k0 + ks * 32 + l32) * 64 + half * 8;
#pragma unroll
        for (int f = 0; f < 4; f++) b[ks][f] = *(const bf16x8*)&Kr[f * 16];
    }

    const u16* Qbase = qb + (size_t)(bh * 2048 + qchunk * 512) * 64;

    f32x16 ZZ;
#pragma unroll
    for (int r = 0; r < 16; r++) ZZ[r] = 0.f;

#define STAGE_Q(buf, qt)                                                        \
    {                                                                           \
        _Pragma("unroll") for (int i = 0; i < 4; i++) {                         \
            int idx = i * 256 + t;                                              \
            int row = idx >> 3;                                                 \
            int blk = (idx & 7) ^ (row & 7);                                    \
            async_copy16(Qbase + (size_t)((qt) * 128 + row) * 64 + blk * 8,     \
                         &Qs[buf][idx * 8]);                                    \
        }                                                                       \
    }

#define COMPUTE_Q(cur, qt)                                                      \
    {                                                                           \
        _Pragma("unroll") for (int sub = 0; sub < 4; sub++) {                   \
            const int row = sub * 32 + l32;                                     \
            const int r7 = row & 7;                                             \
            bf16x8 af[4];                                                       \
            _Pragma("unroll") for (int f = 0; f < 4; f++)                       \
                af[f] = *(const bf16x8*)&Qs[cur][row * 64 +                     \
                                                 (((f * 2 + half)) ^ r7) * 8];  \
            const float* lr = &li_lds[(qt) * 128 + sub * 32 + half * 4];        \
            f32x4 li0 = *(const f32x4*)&lr[0];                                  \
            f32x4 li1 = *(const f32x4*)&lr[8];                                  \
            f32x4 li2 = *(const f32x4*)&lr[16];                                 \
            f32x4 li3 = *(const f32x4*)&lr[24];                                 \
            __builtin_amdgcn_s_setprio(1);                                      \
            _Pragma("unroll") for (int ks = 0; ks < 2; ks++) {                  \
                f32x16 acc = __builtin_amdgcn_mfma_f32_32x32x16_bf16(           \
                    af[0], b[ks][0], ZZ, 0, 0, 0);                              \
                _Pragma("unroll") for (int f = 1; f < 4; f++)                   \
                    acc = __builtin_amdgcn_mfma_f32_32x32x16_bf16(              \
                        af[f], b[ks][f], acc, 0, 0, 0);                         \
                __builtin_amdgcn_s_setprio(0);                                  \
                float c = cs[ks];                                               \
                _Pragma("unroll") for (int r = 0; r < 4; r++)                   \
                    c += __builtin_amdgcn_exp2f(acc[r]) * li0[r];               \
                _Pragma("unroll") for (int r = 0; r < 4; r++)                   \
                    c += __builtin_amdgcn_exp2f(acc[4 + r]) * li1[r];           \
                _Pragma("unroll") for (int r = 0; r < 4; r++)                   \
                    c += __builtin_amdgcn_exp2f(acc[8 + r]) * li2[r];           \
                _Pragma("unroll") for (int r = 0; r < 4; r++)                   \
                    c += __builtin_amdgcn_exp2f(acc[12 + r]) * li3[r];          \
                cs[ks] = c;                                                     \
                __builtin_amdgcn_s_setprio(1);                                  \
            }                                                                   \
            __builtin_amdgcn_s_setprio(0);                                     \
        }                                                                       \
    }

    float cs[2] = {0.f, 0.f};
    __syncthreads();      // li_lds visible (drains only lp loads; no STAGE yet)
    STAGE_Q(0, 0);

    for (int qt = 0; qt < 3; qt++) {   // rolled
        const int cur = qt & 1;
        STAGE_Q(cur ^ 1, qt + 1);      // last vmem issued before the wait
        WAITBAR_4;                     // tile qt landed; qt+1 in flight
        COMPUTE_Q(cur, qt);
        BAR_ONLY;                      // Qs[cur] reads done -> reusable
    }
    WAITBAR_0;                         // peeled last tile (3) in buf 1
    COMPUTE_Q(1, 3);

#pragma unroll
    for (int ks = 0; ks < 2; ks++) {
        float v = cs[ks] + __shfl_xor(cs[ks], 32);
        if (lane < 32)
            cp[qchunk * 65536 + bh * 2048 + k0 + ks * 32 + lane] = v;
    }
}

// values[b][s][h*64+d] = colsum[bh][s] * v[bh][s][d]  (bf16); sums 4 partials
__global__ __launch_bounds__(256) void scale_v(
    const u16* __restrict__ vb, const float* __restrict__ cp,
    u16* __restrict__ valsb) {
    int tid = blockIdx.x * 256 + threadIdx.x;  // 524288 threads, 8 elems each
    int base = tid << 3;
    int bh = base >> 17;           // / (2048*64)
    int rem = base & 131071;
    int s = rem >> 6;
    int d0 = rem & 63;
    int ci = bh * 2048 + s;
    float cs = cp[ci] + cp[65536 + ci] + cp[131072 + ci] + cp[196608 + ci];
    u16x8 v = *(const u16x8*)(vb + (size_t)base);
    u16x8 o;
#pragma unroll
    for (int i = 0; i < 8; i++) o[i] = f2bf(bf2f(v[i]) * cs);
    int b = bh >> 4, h = bh & 15;
    *(u16x8*)&valsb[(size_t)((b * 2048 + s) * 1024) + h * 64 + d0] = o;
}

// ---------------- launch ----------------

extern "C" void kernel_launch(void* const* d_in, const int* in_sizes, int n_in,
                              void* d_out, int out_size, void* d_ws, size_t ws_size,
                              hipStream_t stream) {
    const float* x    = (const float*)d_in[0];   // [2,2048,1024]
    const float* wqkv = (const float*)d_in[1];   // [1024,3072]
    const float* wo   = (const float*)d_in[2];   // [1024,1024]
    float* out = (float*)d_out;                  // [2,2048,1024] fp32
    char* ws = (char*)d_ws;

    u16* xb      = (u16*)(ws);                   // [4096][1024] bf16 (dead after gemm_qkv)
    u16* wqkvT   = (u16*)(ws + 8388608);         // [3072][1024] bf16
    u16* woT     = (u16*)(ws + 14680064);        // [1024][1024] bf16
    u16* qb      = (u16*)(ws + 16777216);        // [32][2048][64] bf16
    u16* kb      = (u16*)(ws + 25165824);
    u16* vb      = (u16*)(ws + 33554432);
    u16* valsb   = (u16*)(ws + 42467328);        // [4096][1024] bf16
    // partial buffers alias xb (dead after gemm_qkv)
    float* lp    = (float*)(ws);                 // [4][32][2048]
    float* cp    = (float*)(ws + 1048576);       // [4][32][2048]

    cast_f32_bf16<<<4096, 256, 0, stream>>>(x, xb, 1048576);
    transpose_cast<<<dim3(96, 32), dim3(32, 8), 0, stream>>>(wqkv, wqkvT, 1024, 3072);
    transpose_cast<<<dim3(32, 32), dim3(32, 8), 0, stream>>>(wo, woT, 1024, 1024);
    gemm_qkv<<<dim3(24, 32), 256, 0, stream>>>(xb, wqkvT, qb, kb, vb);
    attn_pass1<<<1024, 256, 0, stream>>>(qb, kb, lp);
    attn_pass2<<<1024, 256, 0, stream>>>(qb, kb, lp, cp);
    scale_v<<<2048, 256, 0, stream>>>(vb, cp, valsb);
    gemm_out<<<dim3(8, 64), 256, 0, stream>>>(valsb, woT, out);
}